// Round 3
// baseline (395.232 us; speedup 1.0000x reference)
//
#include <hip/hip_runtime.h>

// Single-layer tanh RNN scan: h_t = tanh(x_t @ W_ih^T + b_ih + b_hh + h_{t-1} @ W_hh^T)
// SEQ=2048, BATCH=4096, IN=3, HID=5.
//
// Round-3 change: rounds 1-2 were stuck at ~214 cyc/step with VGPR_Count=80 —
// the PF-step prefetch buffers (96 floats) were in SCRATCH, not registers,
// because they were passed as float* lambda parameters (address-taken defeats
// SROA). Every step's x-read was a ~100-200 cyc scratch load at the head of
// the dependency chain. Fix: macros over directly-named arrays with
// compile-time indices only -> SROA promotes to VGPRs.
//
// Cross-lane h gather: depth-2 DPP butterfly (VALU pipe, no LDS ops):
//   r1 = quad_perm[1,0,3,2] (i^1)   r2 = quad_perm[2,3,0,1] (i^2)
//   r3 = quad_perm[3,2,1,0] (i^3)   r4 = row_half_mirror    (i^7)
//   r5 = hmirr(r1) (i^6)  r6 = hmirr(r2) (i^5)  r7 = hmirr(r3) (i^4)
// Slot s holds h[j ^ d(s)], d = {0,1,2,3,7,6,5,4}; lane-dependent slot->unit
// mapping folded into permuted per-lane weights at init (zero for k>4).
//
// tanh(a) = 1 - 2/(1+e^{2a}); weights/biases pre-scaled by 2*log2(e) so
// e^{2a} = v_exp_f32(a_scaled); rcp via v_rcp_f32.

__device__ __forceinline__ float fast_exp2(float x) {
  return __builtin_amdgcn_exp2f(x);
}
__device__ __forceinline__ float fast_rcp(float x) {
  return __builtin_amdgcn_rcpf(x);
}

#define DPP_QX1  0xB1   // quad_perm [1,0,3,2] : i^1
#define DPP_QX2  0x4E   // quad_perm [2,3,0,1] : i^2
#define DPP_QX3  0x1B   // quad_perm [3,2,1,0] : i^3
#define DPP_HMIR 0x141  // row_half_mirror     : i^7

template <int CTRL>
__device__ __forceinline__ float dpp_mov(float v) {
  return __int_as_float(__builtin_amdgcn_update_dpp(
      0, __float_as_int(v), CTRL, 0xF, 0xF, false));
}

constexpr int S  = 2048;
constexpr int B  = 4096;
constexpr int IN = 3;
constexpr int H  = 5;
constexpr int PF = 16;          // timesteps per prefetch block
constexpr int NBLK = S / PF;    // 128

__global__ void __launch_bounds__(64) rnn_scan_kernel(
    const float* __restrict__ x,    // (S, B, IN)
    const float* __restrict__ h0,   // (1, B, H)
    const float* __restrict__ Wih,  // (H, IN)
    const float* __restrict__ Whh,  // (H, H)
    const float* __restrict__ bih,  // (H)
    const float* __restrict__ bhh,  // (H)
    float* __restrict__ out)        // ys (S,B,H) then h_n (1,B,H)
{
  const int tid = blockIdx.x * 64 + threadIdx.x;
  const int b   = tid >> 3;          // batch element [0, 4096)
  const int j   = tid & 7;           // lane within 8-lane group
  const int jw  = (j < 5) ? j : 4;   // hidden row this lane computes

  // 2*log2(e): fold tanh's input scaling into weights/biases.
  const float c = 2.885390081777927f;

  const float wi0 = c * Wih[jw * 3 + 0];
  const float wi1 = c * Wih[jw * 3 + 1];
  const float wi2 = c * Wih[jw * 3 + 2];
  const float bb  = c * (bih[jw] + bhh[jw]);

  // Butterfly-permuted recurrent weights: slot s sees h[j ^ d(s)],
  // d(s) = s for s<4, 11-s for s>=4.
  float whs[8];
#pragma unroll
  for (int s = 0; s < 8; ++s) {
    const int d = (s < 4) ? s : (11 - s);
    const int k = j ^ d;
    whs[s] = (k <= 4) ? c * Whh[jw * 5 + ((k < 5) ? k : 0)] : 0.0f;
  }
  const float wh0 = whs[0], wh1 = whs[1], wh2 = whs[2], wh3 = whs[3];
  const float wh4 = whs[4], wh5 = whs[5], wh6 = whs[6], wh7 = whs[7];

  float h = h0[b * H + jw];

  const float* xbase = x + (size_t)b * IN;
  float* const op    = out + (size_t)b * H + jw;

  // Double-buffered x prefetch — directly-named arrays, constant indices
  // only, so SROA keeps them in VGPRs (round 1-2 bug: lambda float* params
  // forced these to scratch).
  float x0[PF * 3];
  float x1[PF * 3];

#define LOADBLK(dst, blk_)                                        \
  {                                                               \
    const float* p_ = xbase + (size_t)(blk_) * (PF * B * IN);     \
    _Pragma("unroll")                                             \
    for (int u = 0; u < PF; ++u) {                                \
      dst[u * 3 + 0] = p_[(size_t)u * (B * IN) + 0];              \
      dst[u * 3 + 1] = p_[(size_t)u * (B * IN) + 1];              \
      dst[u * 3 + 2] = p_[(size_t)u * (B * IN) + 2];              \
    }                                                             \
  }

#define COMPUTE(xv, blk_)                                         \
  {                                                               \
    float* o_ = op + (size_t)(blk_) * (PF * B * H);               \
    _Pragma("unroll")                                             \
    for (int u = 0; u < PF; ++u) {                                \
      float xp = fmaf(wi0, xv[u * 3 + 0],                         \
                 fmaf(wi1, xv[u * 3 + 1],                         \
                 fmaf(wi2, xv[u * 3 + 2], bb)));                  \
      float r1 = dpp_mov<DPP_QX1>(h);                             \
      float r2 = dpp_mov<DPP_QX2>(h);                             \
      float r3 = dpp_mov<DPP_QX3>(h);                             \
      float r4 = dpp_mov<DPP_HMIR>(h);                            \
      float r5 = dpp_mov<DPP_HMIR>(r1);                           \
      float r6 = dpp_mov<DPP_HMIR>(r2);                           \
      float r7 = dpp_mov<DPP_HMIR>(r3);                           \
      float a1 = fmaf(wh0, h,                                     \
                 fmaf(wh1, r1,                                    \
                 fmaf(wh2, r2,                                    \
                 fmaf(wh3, r3, xp))));                            \
      float a2 = fmaf(wh4, r4,                                    \
                 fmaf(wh5, r5,                                    \
                 fmaf(wh6, r6, wh7 * r7)));                       \
      float a = a1 + a2;                                          \
      float t = fast_exp2(a);                                     \
      h = fmaf(-2.0f, fast_rcp(1.0f + t), 1.0f);                  \
      o_[(size_t)u * (B * H)] = h;                                \
    }                                                             \
  }

  LOADBLK(x0, 0);
  for (int blk = 0; blk < NBLK; blk += 2) {
    LOADBLK(x1, blk + 1);                 // in flight while computing x0
    COMPUTE(x0, blk);
    if (blk + 2 < NBLK) LOADBLK(x0, blk + 2);
    COMPUTE(x1, blk + 1);
  }

#undef LOADBLK
#undef COMPUTE

  // h_n tail
  out[(size_t)S * B * H + b * H + jw] = h;
}

extern "C" void kernel_launch(void* const* d_in, const int* in_sizes, int n_in,
                              void* d_out, int out_size, void* d_ws, size_t ws_size,
                              hipStream_t stream) {
  const float* x   = (const float*)d_in[0];
  const float* h0  = (const float*)d_in[1];
  const float* Wih = (const float*)d_in[2];
  const float* Whh = (const float*)d_in[3];
  const float* bih = (const float*)d_in[4];
  const float* bhh = (const float*)d_in[5];
  float* out = (float*)d_out;

  // 4096 batch elements * 8 lanes = 32768 threads = 512 blocks of 64.
  dim3 grid((B * 8) / 64), block(64);
  rnn_scan_kernel<<<grid, block, 0, stream>>>(x, h0, Wih, Whh, bih, bhh, out);
}